// Round 12
// baseline (1065.888 us; speedup 1.0000x reference)
//
#include <hip/hip_runtime.h>
#include <math.h>

#define T_LEN 16000
#define NTILE 250          // time tiles per batch row (16000/64)
#define TT 64              // time tile
#define NBLK 2000          // 8 * 250
#define LGRID 500          // layer grid: 4 strided tiles per block

static const int N_RES = 8 * 32 * T_LEN;   // 4,096,000 floats per residual buffer

typedef _Float16 half_t;
typedef __attribute__((ext_vector_type(8))) _Float16 halfx8;
typedef __attribute__((ext_vector_type(4))) _Float16 halfx4;
typedef __attribute__((ext_vector_type(16))) float f32x16;
typedef unsigned int uint32;
typedef unsigned short ushort16;

#define MFMA(a, b, c) __builtin_amdgcn_mfma_f32_32x32x16_f16((a), (b), (c), 0, 0, 0)

static __device__ inline uint32 packpair(float a, float b) {
  half_t ha = (half_t)a, hb = (half_t)b;
  return (uint32)__builtin_bit_cast(ushort16, ha) |
         ((uint32)__builtin_bit_cast(ushort16, hb) << 16);
}

// ---------------- weight repack ----------------
// WaG[l][o=0..127][k=0..127]: k<64: k=2c+s -> hi(Wd[l][o][c][s]); k>=64: lo*2048 of same
// WrG[l][o2=0..31][k=0..255]: 8-wave g-register perm; kk=k&127:
//   mq=kk>>5, ab=(kk>>4)&1, lh=(kk>>3)&1, j=kk&7;
//   m = mq*32 + ab*16 + lh*4 + (j&3) + 8*(j>>2)
//   k<128 hi of Wr[l][m][o2], k>=128 lo*2048  (GEMM2 B-operand = gate regs directly)
// WsS[o=0..31][k=0..511]: kk=k&255: chan=(kk>>1)+(kk&1)*128; k<256 hi Ws[o][chan], k>=256 lo*2048
// We1S[o][k=0..63]: k<32 hi We1[o][k], k>=32 lo*2048
// We2S[o][k=0..511]: k<256 hi We2[o][k], k>=256 lo*2048
__global__ __launch_bounds__(256) void repack_k(
    const float* __restrict__ Wd, const float* __restrict__ Wr,
    const float* __restrict__ Ws, const float* __restrict__ We1,
    const float* __restrict__ We2,
    half_t* __restrict__ WaG, half_t* __restrict__ WrG, half_t* __restrict__ WsS,
    half_t* __restrict__ We1S, half_t* __restrict__ We2S) {
  int i = blockIdx.x * 256 + threadIdx.x;
  if (i < 40 * 128 * 128) {
    int l = i >> 14, r = i & 16383, o = r >> 7, k = r & 127;
    int kk = k & 63, c = kk >> 1, s = kk & 1;
    float w = Wd[(((l * 128 + o) * 32 + c) << 1) + s];
    half_t w0 = (half_t)w;
    WaG[i] = (k < 64) ? w0 : (half_t)((w - (float)w0) * 2048.f);
  }
  if (i < 40 * 32 * 256) {
    int l = i >> 13, r = i & 8191, o2 = r >> 8, k = r & 255;
    int kk = k & 127;
    int mq = kk >> 5, ab = (kk >> 4) & 1, lh = (kk >> 3) & 1, j = kk & 7;
    int m = mq * 32 + ab * 16 + lh * 4 + (j & 3) + ((j >> 2) << 3);
    float w = Wr[(l * 32 + o2) * 128 + m];
    half_t w0 = (half_t)w;
    WrG[i] = (k < 128) ? w0 : (half_t)((w - (float)w0) * 2048.f);
  }
  if (i < 16384) {
    int o = i >> 9, k = i & 511, kk = k & 255;
    int chan = (kk >> 1) + (kk & 1) * 128;
    float w = Ws[o * 256 + chan];
    half_t w0 = (half_t)w;
    WsS[i] = (k < 256) ? w0 : (half_t)((w - (float)w0) * 2048.f);
  }
  if (i < 16384) {
    int o = i >> 6, k = i & 63;
    float w = We1[o * 32 + (k & 31)];
    half_t w0 = (half_t)w;
    We1S[i] = (k < 32) ? w0 : (half_t)((w - (float)w0) * 2048.f);
  }
  if (i < 131072) {
    int o = i >> 9, k = i & 511;
    float w = We2[o * 256 + (k & 255)];
    half_t w0 = (half_t)w;
    We2S[i] = (k < 256) ? w0 : (half_t)((w - (float)w0) * 2048.f);
  }
}

// ---------------- start 1x1 conv, MFMA split-2, chunk-streamed ----------------
__global__ __launch_bounds__(256, 2) void start_k(const float* __restrict__ x,
                                                  const half_t* __restrict__ WsS,
                                                  float* __restrict__ res) {
  __shared__ __align__(16) char sm[51200];
  const int XS_OFF = 0, SKB_OFF = 33792;
  int tid = threadIdx.x;
  int wave = tid >> 6, lane = tid & 63;
  int l31 = lane & 31, lhi = lane >> 5;
  int nh = wave & 1, kh = wave >> 1;
  int b = blockIdx.x / NTILE;
  int t0 = (blockIdx.x % NTILE) * TT;
  int cth = tid >> 3, twh = (tid & 7) * 8;

  f32x16 accH{}, accL{};
#pragma unroll
  for (int p = 0; p < 2; ++p) {
#pragma unroll
    for (int cc = 0; cc < 4; ++cc) {
      const float* p0 = x + ((size_t)b * 256 + cc * 32 + cth) * T_LEN + t0 + twh;
      const float* p1 = p0 + (size_t)128 * T_LEN;
      float u[8], v[8];
      *(float4*)u       = *(const float4*)p0;
      *(float4*)(u + 4) = *(const float4*)(p0 + 4);
      *(float4*)v       = *(const float4*)p1;
      *(float4*)(v + 4) = *(const float4*)(p1 + 4);
#pragma unroll
      for (int j = 0; j < 8; ++j) {
        int t = twh + j;
        int sw = ((t >> 3) & 3) << 5;
        uint32 pk;
        if (p == 0) {
          pk = packpair(u[j], v[j]);
        } else {
          float l0 = (u[j] - (float)(half_t)u[j]) * 2048.f;
          float l1 = (v[j] - (float)(half_t)v[j]) * 2048.f;
          pk = packpair(l0, l1);
        }
        *(uint32*)(sm + XS_OFF + t * 528 + (((cc * 32 + cth) * 4) ^ sw)) = pk;
      }
    }
    __syncthreads();
    {
      int colt = nh * 32 + l31;
      int sw = ((colt >> 3) & 3) << 5;
      const char* xr = sm + XS_OFF + colt * 528;
#pragma unroll
      for (int ks = 0; ks < 8; ++ks) {
        int kg = kh * 8 + ks;
        halfx8 bf = *(const halfx8*)(xr + ((kg * 32 + lhi * 16) ^ sw));
        halfx8 hiA = *(const halfx8*)(WsS + l31 * 512 + kg * 16 + lhi * 8);
        if (p == 0) {
          accH = MFMA(hiA, bf, accH);
          halfx8 loA = *(const halfx8*)(WsS + l31 * 512 + 256 + kg * 16 + lhi * 8);
          accL = MFMA(loA, bf, accL);
        } else {
          accL = MFMA(hiA, bf, accL);
        }
      }
    }
    __syncthreads();
  }
  {
    float* skb = (float*)(sm + SKB_OFF) + kh * 32 * 68;
#pragma unroll
    for (int r = 0; r < 16; ++r) {
      int row = (r & 3) + 8 * (r >> 2) + 4 * lhi;
      skb[row * 68 + nh * 32 + l31] = accH[r] + accL[r] * (1.f / 2048.f);
    }
  }
  __syncthreads();
  {
    const float* s0 = (const float*)(sm + SKB_OFF) + cth * 68 + twh;
    const float* s1 = s0 + 32 * 68;
    float* rp = res + ((size_t)b * 32 + cth) * T_LEN + t0 + twh;
#pragma unroll
    for (int vq = 0; vq < 8; vq += 4) {
      float4 sa = *(const float4*)(s0 + vq);
      float4 sb = *(const float4*)(s1 + vq);
      float4 o;
      o.x = sa.x + sb.x;
      o.y = sa.y + sb.y;
      o.z = sa.z + sb.z;
      o.w = sa.w + sb.w;
      *(float4*)(rp + vq) = o;
    }
  }
}

// ---------------- fused WaveNet layer: 512 threads / 8 waves, 32x32 tiles ----------------
// wave = (mq = wave&3 m-quarter, nh = wave>>2 t-half). VGPR target <=128 -> 4 waves/SIMD.
// LDS: zT 64 x 272B at 0 (17408); skb 4x32x68 f32 at 17408 (34816); total 52224
#define LOAD_TILE(TI, CV, PV)                                              \
  {                                                                        \
    int tl_ = blockIdx.x + (TI) * LGRID;                                   \
    int bb_ = tl_ / NTILE;                                                 \
    int tb_ = (tl_ - bb_ * NTILE) * TT;                                    \
    const float* rip_ = resIn + ((size_t)bb_ * 32 + cth) * T_LEN;          \
    *(float4*)(CV) = *(const float4*)(rip_ + tb_ + twh);                   \
    int tp_ = tb_ + twh - d;                                               \
    if (tp_ >= 0 && (d & 3) == 0) {                                        \
      *(float4*)(PV) = *(const float4*)(rip_ + tp_);                       \
    } else {                                                               \
      _Pragma("unroll")                                                    \
      for (int j_ = 0; j_ < 4; ++j_) {                                     \
        int q_ = tp_ + j_;                                                 \
        (PV)[j_] = (q_ >= 0) ? rip_[q_] : 0.f;                             \
      }                                                                    \
    }                                                                      \
  }

#define STAGE_TILE(CV, PV)                                                 \
  {                                                                        \
    _Pragma("unroll")                                                      \
    for (int j = 0; j < 4; ++j) {                                          \
      int t = twh + j;                                                     \
      int sw = ((t >> 3) & 3) << 5;                                        \
      char* zrow = sm + t * 272;                                           \
      half_t p0 = (half_t)(PV)[j];                                         \
      half_t c0 = (half_t)(CV)[j];                                         \
      float pl = ((PV)[j] - (float)p0) * 2048.f;                           \
      float cl = ((CV)[j] - (float)c0) * 2048.f;                           \
      *(uint32*)(zrow + ((cth * 4) ^ sw))       = packpair((PV)[j], (CV)[j]); \
      *(uint32*)(zrow + ((cth * 4 + 128) ^ sw)) = packpair(pl, cl);        \
    }                                                                      \
  }

#define TILE_BODY(TI, CV, PV, NCV, NPV, PREF)                                  \
  {                                                                            \
    int tile = blockIdx.x + (TI) * LGRID;                                      \
    int b = tile / NTILE;                                                      \
    int t0 = (tile - b * NTILE) * TT;                                          \
    if (PREF) { LOAD_TILE((TI) + 1, NCV, NPV); }                               \
    /* ---- GEMM1: h[mq 32 rows][nh 32 cols] = Wa @ z ---- */                  \
    f32x16 hi{}, lo{};                                                         \
    {                                                                          \
      int colt = nh * 32 + l31;                                                \
      int sw = ((colt >> 3) & 3) << 5;                                         \
      const char* zr = sm + colt * 272;                                        \
      _Pragma("unroll")                                                        \
      for (int ks = 0; ks < 12; ++ks) {                                        \
        int brow = (ks < 4) ? ks * 16                                          \
                            : ((ks < 8) ? (ks & 3) * 16 + 64 : (ks & 3) * 16); \
        halfx8 bf = *(const halfx8*)(zr + ((brow * 2 + lhi * 16) ^ sw));       \
        if (ks < 4)      hi = MFMA(a1h[ks], bf, hi);                           \
        else if (ks < 8) lo = MFMA(a1h[ks & 3], bf, lo);                       \
        else             lo = MFMA(a1l[ks & 3], bf, lo);                       \
      }                                                                        \
    }                                                                          \
    /* ---- gate -> 2 GEMM2 B-fragments (hi/lo) ---- */                        \
    halfx8 ghA, ghB, glA, glB;                                                 \
    _Pragma("unroll")                                                          \
    for (int r = 0; r < 16; ++r) {                                             \
      float ha = hi[r] + lo[r] * (1.f / 2048.f);                               \
      ha = fmaxf(ha, -30.f);                                                   \
      float ea = __expf(-ha);                                                  \
      float ga = (1.f - ea) * __builtin_amdgcn_rcpf(1.f + ea * ea);            \
      half_t ga0 = (half_t)ga;                                                 \
      half_t ga1 = (half_t)((ga - (float)ga0) * 2048.f);                       \
      if (r < 8) { ghA[r] = ga0; glA[r] = ga1; }                               \
      else       { ghB[r - 8] = ga0; glB[r - 8] = ga1; }                       \
    }                                                                          \
    /* ---- GEMM2: skip partial over this wave's k-quarter ---- */             \
    f32x16 shi{}, slo{};                                                       \
    shi = MFMA(wrHiA, ghA, shi);                                               \
    shi = MFMA(wrHiB, ghB, shi);                                               \
    slo = MFMA(wrHiA, glA, slo);                                               \
    slo = MFMA(wrHiB, glB, slo);                                               \
    slo = MFMA(wrLoA, ghA, slo);                                               \
    slo = MFMA(wrLoB, ghB, slo);                                               \
    /* ---- skb quarter-partials ---- */                                       \
    {                                                                          \
      float* skb = (float*)(sm + SKB_OFF) + mq * 32 * 68;                      \
      _Pragma("unroll")                                                        \
      for (int r = 0; r < 16; ++r) {                                           \
        int row = (r & 3) + 8 * (r >> 2) + 4 * lhi;                            \
        skb[row * 68 + nh * 32 + l31] = shi[r] + slo[r] * (1.f / 2048.f);      \
      }                                                                        \
    }                                                                          \
    __syncthreads();                                                           \
    /* ---- writeout: resOut = cur(regs) + sum of 4 quarters ---- */           \
    {                                                                          \
      const float* s = (const float*)(sm + SKB_OFF) + cth * 68 + twh;          \
      float4 q0 = *(const float4*)s;                                           \
      float4 q1 = *(const float4*)(s + 32 * 68);                               \
      float4 q2 = *(const float4*)(s + 64 * 68);                               \
      float4 q3 = *(const float4*)(s + 96 * 68);                               \
      size_t base = ((size_t)b * 32 + cth) * T_LEN + t0 + twh;                 \
      float4 o;                                                                \
      o.x = (CV)[0] + q0.x + q1.x + q2.x + q3.x;                               \
      o.y = (CV)[1] + q0.y + q1.y + q2.y + q3.y;                               \
      o.z = (CV)[2] + q0.z + q1.z + q2.z + q3.z;                               \
      o.w = (CV)[3] + q0.w + q1.w + q2.w + q3.w;                               \
      *(float4*)(resOut + base) = o;                                           \
    }                                                                          \
    if (PREF) {                                                                \
      STAGE_TILE(NCV, NPV)                                                     \
      __syncthreads();                                                         \
    }                                                                          \
  }

__global__ __launch_bounds__(512, 4) void layer_k(const float* __restrict__ resIn,
                                                  float* __restrict__ resOut,
                                                  const half_t* __restrict__ WaL,
                                                  const half_t* __restrict__ WrL,
                                                  int d) {
  __shared__ __align__(16) char sm[52224];
  const int SKB_OFF = 17408;
  int tid = threadIdx.x;
  int wave = tid >> 6, lane = tid & 63;
  int l31 = lane & 31, lhi = lane >> 5;
  int mq = wave & 3, nh = wave >> 2;        // wave owns m-quarter mq, t-half nh
  int cth = tid >> 4, twh = (tid & 15) * 4; // staging/writeout thread mapping

  // ---- per-layer weights into regs (persist across 4 tiles) ----
  halfx8 a1h[4], a1l[4];
  {
    const half_t* wa = WaL + (mq * 32 + l31) * 128 + lhi * 8;
#pragma unroll
    for (int j = 0; j < 4; ++j) {
      a1h[j] = *(const halfx8*)(wa + j * 16);
      a1l[j] = *(const halfx8*)(wa + 64 + j * 16);
    }
  }
  halfx8 wrHiA, wrHiB, wrLoA, wrLoB;
  {
    const half_t* wr = WrL + l31 * 256 + mq * 32 + lhi * 8;
    wrHiA = *(const halfx8*)(wr);
    wrHiB = *(const halfx8*)(wr + 16);
    wrLoA = *(const halfx8*)(wr + 128);
    wrLoB = *(const halfx8*)(wr + 144);
  }

  float cvA[4], pvA[4], cvB[4], pvB[4];
  LOAD_TILE(0, cvA, pvA);
  STAGE_TILE(cvA, pvA)
  __syncthreads();

  TILE_BODY(0, cvA, pvA, cvB, pvB, 1)
  TILE_BODY(1, cvB, pvB, cvA, pvA, 1)
  TILE_BODY(2, cvA, pvA, cvB, pvB, 1)
  TILE_BODY(3, cvB, pvB, cvA, pvA, 0)
}

// ---------------- end: relu(resF-res0) -> relu(We1@.) -> We2@. ----------------
__global__ __launch_bounds__(512, 6) void end_k(const float* __restrict__ resF,
                                                const float* __restrict__ res0,
                                                const half_t* __restrict__ We1S,
                                                const half_t* __restrict__ We2S,
                                                float* __restrict__ out) {
  __shared__ __align__(16) char sm[38912];
  const int H2T_OFF = 0, H1F_OFF = 0, H1T_OFF = 33792;
  int tid = threadIdx.x;
  int b = blockIdx.x / NTILE;
  int t0 = (blockIdx.x % NTILE) * TT;

  {
    int c = tid >> 4, tt4 = (tid & 15) * 4;
    size_t base = ((size_t)b * 32 + c) * T_LEN + t0 + tt4;
    float4 f = *(const float4*)(resF + base);
    float4 z = *(const float4*)(res0 + base);
    float* h1 = (float*)(sm + H1F_OFF) + c * 68 + tt4;
    h1[0] = fmaxf(f.x - z.x, 0.f);
    h1[1] = fmaxf(f.y - z.y, 0.f);
    h1[2] = fmaxf(f.z - z.z, 0.f);
    h1[3] = fmaxf(f.w - z.w, 0.f);
  }
  __syncthreads();
  {
    int t = tid & 63, cg2 = tid >> 6;
    const float* h1 = (const float*)(sm + H1F_OFF);
    halfx4 hi;
#pragma unroll
    for (int j = 0; j < 4; ++j) hi[j] = (half_t)h1[(cg2 * 4 + j) * 68 + t];
    *(halfx4*)(sm + H1T_OFF + t * 80 + cg2 * 8) = hi;
  }
  __syncthreads();

  int wave = tid >> 6, lane = tid & 63;
  int l31 = lane & 31, lhi = lane >> 5;

  f32x16 aHi0{}, aHi1{}, aLo0{}, aLo1{};
  {
    const char* h1t = sm + H1T_OFF;
    const half_t* wp = We1S + (wave * 32 + l31) * 64;
#pragma unroll
    for (int ks = 0; ks < 2; ++ks) {
      halfx8 hiA = *(const halfx8*)(wp + ks * 16 + lhi * 8);
      halfx8 loA = *(const halfx8*)(wp + 32 + ks * 16 + lhi * 8);
      halfx8 B0 = *(const halfx8*)(h1t + l31 * 80 + (ks * 16 + lhi * 8) * 2);
      halfx8 B1 = *(const halfx8*)(h1t + (32 + l31) * 80 + (ks * 16 + lhi * 8) * 2);
      aHi0 = MFMA(hiA, B0, aHi0);
      aLo0 = MFMA(loA, B0, aLo0);
      aHi1 = MFMA(hiA, B1, aHi1);
      aLo1 = MFMA(loA, B1, aLo1);
    }
  }
  {
#pragma unroll
    for (int n = 0; n < 2; ++n) {
      const f32x16& aH = n ? aHi1 : aHi0;
      const f32x16& aL = n ? aLo1 : aLo0;
      int t = n * 32 + l31;
      half_t* row = (half_t*)(sm + H2T_OFF) + t * 264;
#pragma unroll
      for (int g = 0; g < 4; ++g) {
        halfx4 hi;
#pragma unroll
        for (int j = 0; j < 4; ++j) {
          int r = g * 4 + j;
          float v = fmaxf(aH[r] + aL[r] * (1.f / 2048.f), 0.f);
          hi[j] = (half_t)v;
        }
        *(halfx4*)(row + wave * 32 + g * 8 + lhi * 4) = hi;
      }
    }
  }
  __syncthreads();

  f32x16 bHi0{}, bHi1{}, bLo0{}, bLo1{};
  {
    const half_t* wp = We2S + (size_t)(wave * 32 + l31) * 512;
    const char* h2t = sm + H2T_OFF;
#pragma unroll 2
    for (int ks = 0; ks < 16; ++ks) {
      halfx8 hiA = *(const halfx8*)(wp + ks * 16 + lhi * 8);
      halfx8 loA = *(const halfx8*)(wp + 256 + ks * 16 + lhi * 8);
      halfx8 B0 = *(const halfx8*)(h2t + l31 * 528 + (ks * 16 + lhi * 8) * 2);
      halfx8 B1 = *(const halfx8*)(h2t + (32 + l31) * 528 + (ks * 16 + lhi * 8) * 2);
      bHi0 = MFMA(hiA, B0, bHi0);
      bLo0 = MFMA(loA, B0, bLo0);
      bHi1 = MFMA(hiA, B1, bHi1);
      bLo1 = MFMA(loA, B1, bLo1);
    }
  }
  {
#pragma unroll
    for (int n = 0; n < 2; ++n) {
      const f32x16& bH = n ? bHi1 : bHi0;
      const f32x16& bL = n ? bLo1 : bLo0;
      int t = t0 + n * 32 + l31;
#pragma unroll
      for (int r = 0; r < 16; ++r) {
        int o = wave * 32 + (r & 3) + 8 * (r >> 2) + 4 * lhi;
        out[((size_t)b * 256 + o) * T_LEN + t] = bH[r] + bL[r] * (1.f / 2048.f);
      }
    }
  }
}

extern "C" void kernel_launch(void* const* d_in, const int* in_sizes, int n_in,
                              void* d_out, int out_size, void* d_ws, size_t ws_size,
                              hipStream_t stream) {
  const float* x   = (const float*)d_in[0];
  const float* Wst = (const float*)d_in[1];
  const float* Wd  = (const float*)d_in[2];
  const float* Wr  = (const float*)d_in[3];
  const float* We1 = (const float*)d_in[4];
  const float* We2 = (const float*)d_in[5];
  float* out = (float*)d_out;
  float* ws = (float*)d_ws;

  float* resA = ws;                        // start output (skips = resF - resA)
  float* resB = resA + N_RES;
  float* resC = resB + N_RES;
  half_t* WaG  = (half_t*)(resC + N_RES);  // 40*16384
  half_t* WrG  = WaG + 40 * 16384;         // 40*8192
  half_t* WsS  = WrG + 40 * 8192;          // 16384
  half_t* We1S = WsS + 16384;              // 16384
  half_t* We2S = We1S + 16384;             // 131072

  repack_k<<<2560, 256, 0, stream>>>(Wd, Wr, Wst, We1, We2, WaG, WrG, WsS, We1S, We2S);
  start_k<<<NBLK, 256, 0, stream>>>(x, WsS, resA);

  const float* rin = resA;
  for (int l = 0; l < 40; ++l) {
    float* rout = (l & 1) ? resC : resB;
    layer_k<<<LGRID, 512, 0, stream>>>(rin, rout, WaG + l * 16384, WrG + l * 8192,
                                       1 << (l % 10));
    rin = rout;
  }
  end_k<<<NBLK, 512, 0, stream>>>(rin, resA, We1S, We2S, out);
}